// Round 1
// baseline (264.895 us; speedup 1.0000x reference)
//
#include <hip/hip_runtime.h>

#define NV 40962
#define NK 9
#define CIN 32
#define COUT 32
#define NBS 4

// ---------------------------------------------------------------------------
// Kernel 1: transpose x [128 rows = (b*32+c)][V] -> xt [V][128]
// so the per-neighbor gather in the main kernel reads a contiguous 512B row.
// ---------------------------------------------------------------------------
__global__ void __launch_bounds__(256) transpose_x_kernel(
    const float* __restrict__ x, float* __restrict__ xt)
{
    __shared__ float tile[128][65];          // +1 pad: conflict-free both phases
    const int v0 = blockIdx.x * 64;
    const int t  = threadIdx.x;

    const int tv  = t & 63;                  // column within tile
    const int tr0 = t >> 6;                  // 0..3
    #pragma unroll
    for (int i = 0; i < 32; ++i) {
        const int row = tr0 * 32 + i;        // 0..127
        const int v   = v0 + tv;
        tile[row][tv] = (v < NV) ? x[row * NV + v] : 0.0f;
    }
    __syncthreads();

    const int tc = t & 127;                  // bc index, coalesced store
    const int tr = t >> 7;                   // 0..1
    #pragma unroll
    for (int i = 0; i < 32; ++i) {
        const int vl = tr * 32 + i;          // 0..63
        const int gv = v0 + vl;
        if (gv < NV) xt[gv * 128 + tc] = tile[tc][vl];
    }
}

// ---------------------------------------------------------------------------
// Kernel 2: fused gather -> interp (g @ itp_v) -> conv (W @ interp) -> mask
// One thread per (b, v) column. Lane = v (coalesced idx/itp/out).
// W/bias indices are wave-uniform -> scalar loads; per-column accumulators
// live in LDS so the o-loop can stay rolled (no dynamic VGPR indexing).
// ---------------------------------------------------------------------------
__global__ void __launch_bounds__(64) sparse_conv_kernel(
    const float* __restrict__ xt, const int* __restrict__ index,
    const float* __restrict__ itp, const float* __restrict__ w,
    const float* __restrict__ bias, float* __restrict__ out)
{
    __shared__ float accs[COUT][64];         // 8 KB, lane-contiguous
    const int lane = threadIdx.x;            // 0..63
    const int b    = blockIdx.x & 3;
    const int v    = (blockIdx.x >> 2) * 64 + lane;
    if (v >= NV) return;                     // no barriers below: safe

    int nbr[NK];
    #pragma unroll
    for (int k = 0; k < NK; ++k) nbr[k] = index[v * NK + k];

    #pragma unroll
    for (int o = 0; o < COUT; ++o) accs[o][lane] = bias[o];

    bool nz = false;
    const float* itp_v = itp + v * (NK * NK);

    for (int c0 = 0; c0 < CIN; c0 += 4) {    // rolled: 8 channel chunks
        // gather 4 channels x 9 neighbors (16B-aligned float4 from xt)
        float g[4][NK];
        #pragma unroll
        for (int k = 0; k < NK; ++k) {
            const float4 q = *(const float4*)(xt + nbr[k] * 128 + b * 32 + c0);
            g[0][k] = q.x; g[1][k] = q.y; g[2][k] = q.z; g[3][k] = q.w;
            nz = nz || (q.x != 0.0f) || (q.y != 0.0f) ||
                       (q.z != 0.0f) || (q.w != 0.0f);
        }

        // interp[cc][j] = sum_k g[cc][k] * itp_v[k][j]   (all reg-resident)
        float interp[4][NK];
        #pragma unroll
        for (int cc = 0; cc < 4; ++cc)
            #pragma unroll
            for (int j = 0; j < NK; ++j) interp[cc][j] = 0.0f;
        #pragma unroll
        for (int k = 0; k < NK; ++k) {
            float row[NK];
            #pragma unroll
            for (int j = 0; j < NK; ++j) row[j] = itp_v[k * NK + j];
            #pragma unroll
            for (int cc = 0; cc < 4; ++cc)
                #pragma unroll
                for (int j = 0; j < NK; ++j)
                    interp[cc][j] += g[cc][k] * row[j];
        }

        // conv: acc[o] += sum_{cc,j} interp[cc][j] * w[o][c0+cc][j]
        // o-loop rolled; w index wave-uniform -> s_load; acc in LDS.
        const float* wc = w + c0 * NK;
        for (int o = 0; o < COUT; ++o) {
            float a = accs[o][lane];
            const float* wo = wc + o * (CIN * NK);
            #pragma unroll
            for (int cc = 0; cc < 4; ++cc)
                #pragma unroll
                for (int j = 0; j < NK; ++j)
                    a += interp[cc][j] * wo[cc * NK + j];
            accs[o][lane] = a;
        }
    }

    const float m = nz ? 1.0f : 0.0f;
    float* outp = out + b * (COUT * NV) + v;
    #pragma unroll
    for (int o = 0; o < COUT; ++o) outp[o * NV] = accs[o][lane] * m;
}

// ---------------------------------------------------------------------------
extern "C" void kernel_launch(void* const* d_in, const int* in_sizes, int n_in,
                              void* d_out, int out_size, void* d_ws, size_t ws_size,
                              hipStream_t stream)
{
    const float* x     = (const float*)d_in[0];
    const int*   index = (const int*)  d_in[1];
    const float* itp   = (const float*)d_in[2];
    const float* w     = (const float*)d_in[3];
    const float* bias  = (const float*)d_in[4];
    float*       out   = (float*)d_out;
    float*       xt    = (float*)d_ws;        // NV*128 floats = 20.97 MB

    const int nvb = (NV + 63) / 64;           // 641
    hipLaunchKernelGGL(transpose_x_kernel, dim3(nvb), dim3(256), 0, stream, x, xt);
    hipLaunchKernelGGL(sparse_conv_kernel, dim3(nvb * NBS), dim3(64), 0, stream,
                       xt, index, itp, w, bias, out);
}

// Round 2
// 174.123 us; speedup vs baseline: 1.5213x; 1.5213x over previous
//
#include <hip/hip_runtime.h>

#define NV 40962
#define NK 9
#define CIN 32
#define COUT 32
#define NBS 4

typedef __attribute__((ext_vector_type(8))) short bf16x8;
typedef __attribute__((ext_vector_type(4))) float f32x4;

// round-to-nearest-even f32 -> bf16 pair packed in a dword
__device__ __forceinline__ unsigned bf16pair(float a, float b) {
    unsigned ua = __float_as_uint(a), ub = __float_as_uint(b);
    ua = (ua + 0x7FFFu + ((ua >> 16) & 1u)) >> 16;
    ub = (ub + 0x7FFFu + ((ub >> 16) & 1u)) & 0xFFFF0000u;
    return (ua & 0xFFFFu) | ub;
}

// ---------------------------------------------------------------------------
// Kernel 1: x [128 rows=(b*32+c)][V] f32 -> xt [V][128] bf16 (halves gather BW)
// ---------------------------------------------------------------------------
__global__ void __launch_bounds__(256) transpose_x_bf16(
    const float* __restrict__ x, unsigned short* __restrict__ xt)
{
    __shared__ float tile[128][65];
    const int v0 = blockIdx.x * 64;
    const int t  = threadIdx.x;

    const int tv  = t & 63;
    const int tr0 = t >> 6;
    #pragma unroll
    for (int i = 0; i < 32; ++i) {
        const int row = tr0 * 32 + i;
        const int v   = v0 + tv;
        tile[row][tv] = (v < NV) ? x[row * NV + v] : 0.0f;
    }
    __syncthreads();

    const int tc2 = t & 63;                  // dword index: channels 2*tc2, 2*tc2+1
    const int tr  = t >> 6;                  // 0..3
    #pragma unroll
    for (int i = 0; i < 16; ++i) {
        const int vl = tr * 16 + i;
        const int gv = v0 + vl;
        if (gv < NV) {
            ((unsigned*)xt)[gv * 64 + tc2] =
                bf16pair(tile[tc2 * 2][vl], tile[tc2 * 2 + 1][vl]);
        }
    }
}

// ---------------------------------------------------------------------------
// Kernel 2: conv weight f32 [o][c][j] -> bf16 [o][k=c*9+j]  (GEMM K-order)
// ---------------------------------------------------------------------------
__global__ void __launch_bounds__(256) convert_w_bf16(
    const float* __restrict__ w, unsigned short* __restrict__ wbf)
{
    const int i = blockIdx.x * 256 + threadIdx.x;
    if (i < COUT * CIN * NK) {
        unsigned u = __float_as_uint(w[i]);
        wbf[i] = (unsigned short)((u + 0x7FFFu + ((u >> 16) & 1u)) >> 16);
    }
}

// ---------------------------------------------------------------------------
// Kernel 3: fused gather -> interp (VALU f32) -> conv (MFMA bf16) -> mask
// Block = 256 thr: 16 vertices x 4 batches = 64 cols; col = b*16 + v_local.
// Phase 1: thread (col, q=t>>6) gathers channels q*8..q*8+7, computes interp,
//          packs bf16 into Alds[64][296] (k = c*9+j, 288 used, pad->2-way free).
// Phase 2: wave w = batch w: 16 cols x 32 o via 2x9 mfma_f32_16x16x32_bf16;
//          A = W[o][k] from global (L2-hot), B = interp from LDS.
// ---------------------------------------------------------------------------
#define APAD 296

__global__ void __launch_bounds__(256) sparse_conv_mfma(
    const unsigned short* __restrict__ xt, const int* __restrict__ index,
    const float* __restrict__ itp, const unsigned short* __restrict__ wbf,
    const float* __restrict__ bias, float* __restrict__ out)
{
    __shared__ unsigned short Alds[64 * APAD];   // 37888 B
    __shared__ float itp_s[16 * 81];             // 5184 B
    __shared__ float nz_s[64];

    const int t  = threadIdx.x;
    const int v0 = blockIdx.x * 16;

    // stage itp for this block's 16 vertices (perfectly coalesced)
    {
        const long base = (long)v0 * 81;
        #pragma unroll
        for (int i = t; i < 16 * 81; i += 256)
            itp_s[i] = (base + i < (long)NV * 81) ? itp[base + i] : 0.0f;
    }
    if (t < 64) nz_s[t] = 0.0f;
    __syncthreads();

    // ---- Phase 1 ----
    const int col = t & 63;                  // b*16 + v_local
    const int b   = col >> 4;
    const int vl  = col & 15;
    const int q   = t >> 6;                  // channel group: c = q*8 .. q*8+7
    const int v   = min(v0 + vl, NV - 1);

    int nbr[NK];
    #pragma unroll
    for (int k = 0; k < NK; ++k) nbr[k] = index[v * NK + k];

    unsigned nzbits = 0;
    #pragma unroll
    for (int half = 0; half < 2; ++half) {
        const int c0 = q * 8 + half * 4;

        // gather 4 channels x 9 neighbors (8B bf16 loads)
        float g[4][NK];
        #pragma unroll
        for (int k = 0; k < NK; ++k) {
            const uint2 u2 = *(const uint2*)(xt + nbr[k] * 128 + b * 32 + c0);
            nzbits |= (u2.x | u2.y) & 0x7FFF7FFFu;     // +/-0 counts as zero
            g[0][k] = __uint_as_float(u2.x << 16);
            g[1][k] = __uint_as_float(u2.x & 0xFFFF0000u);
            g[2][k] = __uint_as_float(u2.y << 16);
            g[3][k] = __uint_as_float(u2.y & 0xFFFF0000u);
        }

        // interp[cc][j] = sum_k g[cc][k] * itp_v[k][j]  (f32, reg-resident)
        float acc[4][NK];
        #pragma unroll
        for (int cc = 0; cc < 4; ++cc)
            #pragma unroll
            for (int j = 0; j < NK; ++j) acc[cc][j] = 0.0f;
        #pragma unroll
        for (int k = 0; k < NK; ++k) {
            float row[NK];
            #pragma unroll
            for (int j = 0; j < NK; ++j) row[j] = itp_s[vl * 81 + k * 9 + j];
            #pragma unroll
            for (int cc = 0; cc < 4; ++cc)
                #pragma unroll
                for (int j = 0; j < NK; ++j) acc[cc][j] += g[cc][k] * row[j];
        }

        // pack bf16 -> Alds[col][k], k = (c0+cc)*9 + j  (36 contiguous elems)
        float fl[36];
        #pragma unroll
        for (int cc = 0; cc < 4; ++cc)
            #pragma unroll
            for (int j = 0; j < NK; ++j) fl[cc * 9 + j] = acc[cc][j];
        unsigned* dst = (unsigned*)&Alds[col * APAD + c0 * 9];
        #pragma unroll
        for (int i = 0; i < 18; ++i) dst[i] = bf16pair(fl[2 * i], fl[2 * i + 1]);
    }
    if (nzbits) nz_s[col] = 1.0f;            // benign same-value race

    __syncthreads();

    // ---- Phase 2: MFMA ----
    const int w    = t >> 6;                 // wave id == batch b
    const int L    = t & 63;
    const int n16  = L & 15;                 // N index (column within wave tile)
    const int quad = L >> 4;                 // K-quad
    const int colw = w * 16 + n16;

    f32x4 acc0 = {0.f, 0.f, 0.f, 0.f};
    f32x4 acc1 = {0.f, 0.f, 0.f, 0.f};
    #pragma unroll
    for (int ks = 0; ks < 9; ++ks) {
        const int ko = ks * 32 + quad * 8;
        const bf16x8 a0 = *(const bf16x8*)(wbf + n16 * 288 + ko);
        const bf16x8 a1 = *(const bf16x8*)(wbf + (n16 + 16) * 288 + ko);
        const bf16x8 bf = *(const bf16x8*)(&Alds[colw * APAD + ko]);
        acc0 = __builtin_amdgcn_mfma_f32_16x16x32_bf16(a0, bf, acc0, 0, 0, 0);
        acc1 = __builtin_amdgcn_mfma_f32_16x16x32_bf16(a1, bf, acc1, 0, 0, 0);
    }

    // epilogue: D[m=o][n=col]; lane holds o = quad*4+r (+16), col = n16
    const int vv = v0 + n16;
    if (vv < NV) {
        const float m = nz_s[colw];
        float* outb = out + (size_t)w * (COUT * NV) + vv;
        #pragma unroll
        for (int r = 0; r < 4; ++r) {
            const int o0 = quad * 4 + r;
            outb[(size_t)o0 * NV]        = (acc0[r] + bias[o0]) * m;
            outb[(size_t)(o0 + 16) * NV] = (acc1[r] + bias[o0 + 16]) * m;
        }
    }
}

// ---------------------------------------------------------------------------
extern "C" void kernel_launch(void* const* d_in, const int* in_sizes, int n_in,
                              void* d_out, int out_size, void* d_ws, size_t ws_size,
                              hipStream_t stream)
{
    const float* x     = (const float*)d_in[0];
    const int*   index = (const int*)  d_in[1];
    const float* itp   = (const float*)d_in[2];
    const float* w     = (const float*)d_in[3];
    const float* bias  = (const float*)d_in[4];
    float*       out   = (float*)d_out;

    unsigned short* xt  = (unsigned short*)d_ws;                 // NV*128*2 B
    unsigned short* wbf = (unsigned short*)((char*)d_ws + (size_t)NV * 128 * 2);

    const int nvb = (NV + 63) / 64;          // 641
    hipLaunchKernelGGL(convert_w_bf16, dim3((COUT * CIN * NK + 255) / 256),
                       dim3(256), 0, stream, w, wbf);
    hipLaunchKernelGGL(transpose_x_bf16, dim3(nvb), dim3(256), 0, stream, x, xt);
    hipLaunchKernelGGL(sparse_conv_mfma, dim3((NV + 15) / 16), dim3(256), 0,
                       stream, xt, index, itp, wbf, bias, out);
}